// Round 1
// baseline (585.822 us; speedup 1.0000x reference)
//
#include <hip/hip_runtime.h>
#include <cstdint>

// FlashCrossAttention round 1: correctness-first full bf16 pipeline.
// B=4, Td=Te=2048, D=1024, H=16, hd=64.

#define DEVI __device__ __forceinline__

typedef float f32x4 __attribute__((ext_vector_type(4)));
typedef __bf16 bf16x8 __attribute__((ext_vector_type(8)));

DEVI unsigned short f2bf(float f) {
  union { float f; unsigned u; } v; v.f = f;
  unsigned r = v.u + 0x7FFFu + ((v.u >> 16) & 1u);   // RTNE
  return (unsigned short)(r >> 16);
}
DEVI float bf2f(unsigned short h) {
  union { unsigned u; float f; } v; v.u = ((unsigned)h) << 16;
  return v.f;
}
DEVI f32x4 mfma16(bf16x8 a, bf16x8 b, f32x4 c) {
  return __builtin_amdgcn_mfma_f32_16x16x32_bf16(a, b, c, 0, 0, 0);
}
DEVI void gl_lds16(const void* g, void* l) {
  __builtin_amdgcn_global_load_lds((const __attribute__((address_space(1))) void*)g,
                                   (__attribute__((address_space(3))) void*)l,
                                   16, 0, 0);
}

// ---------------- elementwise helpers ----------------

__global__ void conv_bf16_k(const float* __restrict__ in, unsigned short* __restrict__ out, long n4) {
  long i = (long)blockIdx.x * blockDim.x + threadIdx.x;
  if (i >= n4) return;
  const float4 v = ((const float4*)in)[i];
  ushort4 o;
  o.x = f2bf(v.x); o.y = f2bf(v.y); o.z = f2bf(v.z); o.w = f2bf(v.w);
  ((ushort4*)out)[i] = o;
}

// one block per row of 1024; 256 threads * float4
__global__ void rmsnorm_k(const float* __restrict__ x, const float* __restrict__ wgt,
                          unsigned short* __restrict__ xn) {
  const int row = blockIdx.x;
  const int t = threadIdx.x;
  const float4 v = ((const float4*)(x + (long)row * 1024))[t];
  float ss = v.x * v.x + v.y * v.y + v.z * v.z + v.w * v.w;
#pragma unroll
  for (int m = 1; m < 64; m <<= 1) ss += __shfl_xor(ss, m, 64);
  __shared__ float red[4];
  if ((t & 63) == 0) red[t >> 6] = ss;
  __syncthreads();
  const float tot = red[0] + red[1] + red[2] + red[3];
  const float rms = rsqrtf(tot * (1.f / 1024.f) + 1e-5f);
  const float4 wv = ((const float4*)wgt)[t];
  ushort4 o;
  o.x = f2bf(v.x * rms * wv.x);
  o.y = f2bf(v.y * rms * wv.y);
  o.z = f2bf(v.z * rms * wv.z);
  o.w = f2bf(v.w * rms * wv.w);
  ((ushort4*)(xn + (long)row * 1024))[t] = o;
}

// cos/sin table: tab[0..65535]=cos(t*inv_freq[j]), tab[65536..]=sin  (t<2048, j<32)
__global__ void rope_tab_k(float* __restrict__ tab) {
  const int i = blockIdx.x * 256 + threadIdx.x;   // 65536 threads
  const int t = i >> 5, j = i & 31;
  const float inv = powf(10000.f, -(float)j * (1.f / 32.f));
  const float a = (float)t * inv;
  tab[i] = cosf(a);
  tab[65536 + i] = sinf(a);
}

// in-place RoPE on head-major [B*H][T=2048][64] bf16; scale folded (q: 1/8)
__global__ void rope_apply_k(unsigned short* __restrict__ qk, const float* __restrict__ tab, float scale) {
  const long i = (long)blockIdx.x * 256 + threadIdx.x;  // B*H*T*32 threads
  const int j = (int)(i & 31);
  const long row = i >> 5;
  const int t = (int)(row & 2047);
  unsigned short* p = qk + row * 64;
  const float c = tab[t * 32 + j], s = tab[65536 + t * 32 + j];
  const float x1 = bf2f(p[j]), x2 = bf2f(p[j + 32]);
  p[j]      = f2bf((x1 * c - x2 * s) * scale);
  p[j + 32] = f2bf((x2 * c + x1 * s) * scale);
}

// ---------------- GEMM: C[M,N] = A[M,K] * B^T  (B stored [N][K] row-major) ----------------
// m97 structure: 128x128 tile, BK=32, 4 waves (2x2 of 64x64), global_load_lds w=16,
// double-buffered LDS, XOR chunk swizzle on both sides (rule #21).
// EPI 0: scatter bf16 to Q head-major [B][H][2048][64]
// EPI 1: cols<1024 -> K head-major; cols>=1024 -> V transposed [B][H][64][2048]
// EPI 2: fp32 out = acc + resid (N==1024)
template <int EPI>
__launch_bounds__(256, 2)
__global__ void gemm_bt_k(const unsigned short* __restrict__ A,
                          const unsigned short* __restrict__ Bw,
                          unsigned short* __restrict__ o_bf0,
                          unsigned short* __restrict__ o_bf1,
                          float* __restrict__ o_f32,
                          const float* __restrict__ resid,
                          int N, int K) {
  __shared__ unsigned short As[2][128 * 32];
  __shared__ unsigned short Bs[2][128 * 32];
  const int tix = threadIdx.x;
  const int w = tix >> 6, l = tix & 63;
  const int wr = w >> 1, wc = w & 1;
  const int lr = l & 15, lg = l >> 4;
  const long bm = blockIdx.y, bn = blockIdx.x;
  const long arow0 = bm * 128, brow0 = bn * 128;

  f32x4 acc[4][4] = {};

  const int r2 = tix >> 2, c2 = tix & 3;      // staging: row(0..63), lds slot(0..3)
  const int sw2 = c2 ^ (r2 & 3);              // source chunk (XOR involution)

  auto stage = [&](int buf, int kt) {
    const long k0 = (long)kt * 32;
    const unsigned short* ga  = A  + (arow0 + r2) * K + k0 + sw2 * 8;
    const unsigned short* ga2 = A  + (arow0 + 64 + r2) * K + k0 + sw2 * 8;
    const unsigned short* gb  = Bw + (brow0 + r2) * K + k0 + sw2 * 8;
    const unsigned short* gb2 = Bw + (brow0 + 64 + r2) * K + k0 + sw2 * 8;
    char* la = (char*)&As[buf][0] + w * 1024;
    char* lb = (char*)&Bs[buf][0] + w * 1024;
    gl_lds16(ga,  la);
    gl_lds16(ga2, la + 4096);
    gl_lds16(gb,  lb);
    gl_lds16(gb2, lb + 4096);
  };

  auto lds_off = [&](int row, int chunk) { return row * 32 + ((chunk ^ (row & 3)) << 3); };

  auto compute = [&](int buf) {
    bf16x8 af[4], bv[4];
#pragma unroll
    for (int m = 0; m < 4; ++m)
      af[m] = *(const bf16x8*)&As[buf][lds_off(wr * 64 + m * 16 + lr, lg)];
#pragma unroll
    for (int n = 0; n < 4; ++n)
      bv[n] = *(const bf16x8*)&Bs[buf][lds_off(wc * 64 + n * 16 + lr, lg)];
#pragma unroll
    for (int m = 0; m < 4; ++m)
#pragma unroll
      for (int n = 0; n < 4; ++n)
        acc[m][n] = mfma16(af[m], bv[n], acc[m][n]);
  };

  const int nk = K >> 5;
  stage(0, 0);
  __syncthreads();
  int buf = 0;
#pragma unroll 1
  for (int kt = 0; kt < nk - 1; ++kt) {
    stage(buf ^ 1, kt + 1);
    compute(buf);
    __syncthreads();
    buf ^= 1;
  }
  compute(buf);

#pragma unroll
  for (int m = 0; m < 4; ++m) {
#pragma unroll
    for (int n = 0; n < 4; ++n) {
#pragma unroll
      for (int r = 0; r < 4; ++r) {
        const long grow = arow0 + wr * 64 + m * 16 + lg * 4 + r;  // token idx (b*2048+t)
        const long gcol = brow0 + wc * 64 + n * 16 + lr;          // feature
        const float v = acc[m][n][r];
        if constexpr (EPI == 0) {
          const long b = grow >> 11, t = grow & 2047;
          const long hh = gcol >> 6, d = gcol & 63;
          o_bf0[(((b * 16) + hh) * 2048 + t) * 64 + d] = f2bf(v);
        } else if constexpr (EPI == 1) {
          const long b = grow >> 11, t = grow & 2047;
          if (gcol < 1024) {
            const long hh = gcol >> 6, d = gcol & 63;
            o_bf0[(((b * 16) + hh) * 2048 + t) * 64 + d] = f2bf(v);
          } else {
            const long o2 = gcol - 1024;
            const long hh = o2 >> 6, d = o2 & 63;
            o_bf1[(((b * 16) + hh) * 64 + d) * 2048 + t] = f2bf(v);
          }
        } else {
          const long idx = grow * 1024 + gcol;
          o_f32[idx] = v + resid[idx];
        }
      }
    }
  }
  (void)N;
}

// ---------------- flash cross-attention ----------------
// grid (Td/64, B*H), 256 threads (4 waves); wave owns 16 q rows.
// Q head-major [bh][2048][64] (pre-scaled 1/8, RoPE'd); K head-major; V transposed [bh][64][2048].
__launch_bounds__(256, 2)
__global__ void attn_k(const unsigned short* __restrict__ Qh,
                       const unsigned short* __restrict__ Kh,
                       const unsigned short* __restrict__ Vt,
                       unsigned short* __restrict__ aout) {
  __shared__ unsigned short Ks[2][32 * 64];   // [kv 32][hd 64], swizzled chunks
  __shared__ unsigned short Vs[2][64 * 32];   // [d 64][kv 32], swizzled chunks
  __shared__ unsigned short Ps[4][16 * 32];   // per-wave P^ transpose buffer
  const int tix = threadIdx.x;
  const int w = tix >> 6, l = tix & 63;
  const int lr = l & 15, lg = l >> 4;
  const int bh = blockIdx.y;
  const long b = bh >> 4, h = bh & 15;
  const int q0 = blockIdx.x * 64 + w * 16;
  const unsigned short* Qb = Qh + (long)bh * 2048 * 64;
  const unsigned short* Kb = Kh + (long)bh * 2048 * 64;
  const unsigned short* Vb = Vt + (long)bh * 64 * 2048;

  const bf16x8 qa0 = *(const bf16x8*)(Qb + (long)(q0 + lr) * 64 + lg * 8);
  const bf16x8 qa1 = *(const bf16x8*)(Qb + (long)(q0 + lr) * 64 + 32 + lg * 8);

  float mrow[4] = {-INFINITY, -INFINITY, -INFINITY, -INFINITY};
  float lrow[4] = {0.f, 0.f, 0.f, 0.f};
  f32x4 oacc[4] = {};

  const int kr = tix >> 3, kc = tix & 7;      // K stage: row 0..31, slot 0..7 (128B rows)
  const int ksw = kc ^ (kr & 7);
  const int vr = tix >> 2, vc = tix & 3;      // V stage: row 0..63, slot 0..3 (64B rows)
  const int vsw = vc ^ (vr & 3);

  auto stage = [&](int buf, int kt) {
    const unsigned short* gk = Kb + ((long)kt * 32 + kr) * 64 + ksw * 8;
    const unsigned short* gv = Vb + (long)vr * 2048 + kt * 32 + vsw * 8;
    gl_lds16(gk, (char*)&Ks[buf][0] + w * 1024);
    gl_lds16(gv, (char*)&Vs[buf][0] + w * 1024);
  };

  auto koff = [&](int row, int chunk) { return row * 64 + ((chunk ^ (row & 7)) << 3); };
  auto voff = [&](int row, int chunk) { return row * 32 + ((chunk ^ (row & 3)) << 3); };

  auto compute = [&](int buf) {
    f32x4 s0 = {0.f, 0.f, 0.f, 0.f}, s1 = {0.f, 0.f, 0.f, 0.f};
    bf16x8 kb;
    kb = *(const bf16x8*)&Ks[buf][koff(lr,      lg)];      s0 = mfma16(qa0, kb, s0);
    kb = *(const bf16x8*)&Ks[buf][koff(lr,      4 + lg)];  s0 = mfma16(qa1, kb, s0);
    kb = *(const bf16x8*)&Ks[buf][koff(16 + lr, lg)];      s1 = mfma16(qa0, kb, s1);
    kb = *(const bf16x8*)&Ks[buf][koff(16 + lr, 4 + lg)];  s1 = mfma16(qa1, kb, s1);

    // online softmax over this 32-kv tile; rows q = lg*4+r live in the 16-lane group
    float tm[4], ts[4], p0[4], p1[4], al[4];
#pragma unroll
    for (int r = 0; r < 4; ++r) tm[r] = fmaxf(s0[r], s1[r]);
#pragma unroll
    for (int msk = 1; msk < 16; msk <<= 1)
#pragma unroll
      for (int r = 0; r < 4; ++r) tm[r] = fmaxf(tm[r], __shfl_xor(tm[r], msk, 64));
#pragma unroll
    for (int r = 0; r < 4; ++r) {
      const float mn = fmaxf(mrow[r], tm[r]);
      al[r] = __expf(mrow[r] - mn);
      mrow[r] = mn;
      p0[r] = __expf(s0[r] - mn);
      p1[r] = __expf(s1[r] - mn);
      ts[r] = p0[r] + p1[r];
    }
#pragma unroll
    for (int msk = 1; msk < 16; msk <<= 1)
#pragma unroll
      for (int r = 0; r < 4; ++r) ts[r] += __shfl_xor(ts[r], msk, 64);
#pragma unroll
    for (int r = 0; r < 4; ++r) lrow[r] = lrow[r] * al[r] + ts[r];
#pragma unroll
    for (int n = 0; n < 4; ++n)
#pragma unroll
      for (int r = 0; r < 4; ++r) oacc[n][r] *= al[r];

    // transpose P through per-wave LDS (swizzled), then PV
    unsigned short* pp = &Ps[w][0];
#pragma unroll
    for (int r = 0; r < 4; ++r) {
      const int q = lg * 4 + r;
      pp[q * 32 + (((lr >> 3) ^ (q & 3)) << 3) + (lr & 7)]        = f2bf(p0[r]);
      pp[q * 32 + ((((16 + lr) >> 3) ^ (q & 3)) << 3) + (lr & 7)] = f2bf(p1[r]);
    }
    asm volatile("s_waitcnt lgkmcnt(0)" ::: "memory");
    const bf16x8 pa = *(const bf16x8*)&Ps[w][lr * 32 + ((lg ^ (lr & 3)) << 3)];
#pragma unroll
    for (int n = 0; n < 4; ++n) {
      const bf16x8 vb = *(const bf16x8*)&Vs[buf][voff(n * 16 + lr, lg)];
      oacc[n] = mfma16(pa, vb, oacc[n]);
    }
  };

  stage(0, 0);
  __syncthreads();
  int buf = 0;
#pragma unroll 1
  for (int kt = 0; kt < 63; ++kt) {
    stage(buf ^ 1, kt + 1);
    compute(buf);
    __syncthreads();
    buf ^= 1;
  }
  compute(buf);

#pragma unroll
  for (int n = 0; n < 4; ++n)
#pragma unroll
    for (int r = 0; r < 4; ++r) {
      const long t = q0 + lg * 4 + r;
      const long dcol = h * 64 + n * 16 + lr;
      aout[(b * 2048 + t) * 1024 + dcol] = f2bf(oacc[n][r] / lrow[r]);
    }
}

// ---------------- launch ----------------

extern "C" void kernel_launch(void* const* d_in, const int* in_sizes, int n_in,
                              void* d_out, int out_size, void* d_ws, size_t ws_size,
                              hipStream_t stream) {
  const float* x   = (const float*)d_in[0];
  const float* enc = (const float*)d_in[1];
  const float* nw  = (const float*)d_in[2];
  const float* Wq  = (const float*)d_in[3];
  const float* Wkv = (const float*)d_in[4];
  const float* Wo  = (const float*)d_in[5];
  float* out = (float*)d_out;
  char* ws = (char*)d_ws;
  const long MB = 1024 * 1024;
  unsigned short* xn   = (unsigned short*)(ws);            // 16MB (reused as attn_out)
  unsigned short* encb = (unsigned short*)(ws + 16 * MB);  // 16MB
  unsigned short* wqb  = (unsigned short*)(ws + 32 * MB);  // 2MB
  unsigned short* wkvb = (unsigned short*)(ws + 34 * MB);  // 4MB
  unsigned short* wob  = (unsigned short*)(ws + 38 * MB);  // 2MB
  unsigned short* Qh   = (unsigned short*)(ws + 40 * MB);  // 16MB
  unsigned short* Kh   = (unsigned short*)(ws + 56 * MB);  // 16MB
  unsigned short* Vt   = (unsigned short*)(ws + 72 * MB);  // 16MB
  float* tab           = (float*)(ws + 88 * MB);           // 512KB
  unsigned short* aout = xn;

  conv_bf16_k<<<1024, 256, 0, stream>>>(Wq, wqb, 262144);
  conv_bf16_k<<<2048, 256, 0, stream>>>(Wkv, wkvb, 524288);
  conv_bf16_k<<<1024, 256, 0, stream>>>(Wo, wob, 262144);
  conv_bf16_k<<<8192, 256, 0, stream>>>(enc, encb, 2097152);
  rmsnorm_k<<<8192, 256, 0, stream>>>(x, nw, xn);
  rope_tab_k<<<256, 256, 0, stream>>>(tab);
  gemm_bt_k<0><<<dim3(8, 64), 256, 0, stream>>>(xn, wqb, Qh, nullptr, nullptr, nullptr, 1024, 1024);
  gemm_bt_k<1><<<dim3(16, 64), 256, 0, stream>>>(encb, wkvb, Kh, Vt, nullptr, nullptr, 2048, 1024);
  rope_apply_k<<<16384, 256, 0, stream>>>(Qh, tab, 0.125f);
  rope_apply_k<<<16384, 256, 0, stream>>>(Kh, tab, 1.0f);
  attn_k<<<dim3(32, 64), 256, 0, stream>>>(Qh, Kh, Vt, aout);
  gemm_bt_k<2><<<dim3(8, 64), 256, 0, stream>>>(aout, wob, nullptr, nullptr, out, x, 1024, 1024);
  (void)in_sizes; (void)n_in; (void)out_size; (void)ws_size;
}

// Round 2
// 512.793 us; speedup vs baseline: 1.1424x; 1.1424x over previous
//
#include <hip/hip_runtime.h>
#include <cstdint>

// FlashCrossAttention round 2: swapped-operand 32x32 MFMA attention,
// lane-local softmax, no LDS / no barriers in attention.
// B=4, Td=Te=2048, D=1024, H=16, hd=64.

#define DEVI __device__ __forceinline__

typedef float f32x4 __attribute__((ext_vector_type(4)));
typedef float f32x16 __attribute__((ext_vector_type(16)));
typedef __bf16 bf16x8 __attribute__((ext_vector_type(8)));

DEVI unsigned short f2bf(float f) {
  union { float f; unsigned u; } v; v.f = f;
  unsigned r = v.u + 0x7FFFu + ((v.u >> 16) & 1u);   // RTNE
  return (unsigned short)(r >> 16);
}
DEVI float bf2f(unsigned short h) {
  union { unsigned u; float f; } v; v.u = ((unsigned)h) << 16;
  return v.f;
}
DEVI f32x4 mfma16(bf16x8 a, bf16x8 b, f32x4 c) {
  return __builtin_amdgcn_mfma_f32_16x16x32_bf16(a, b, c, 0, 0, 0);
}
DEVI f32x16 mfma32(bf16x8 a, bf16x8 b, f32x16 c) {
  return __builtin_amdgcn_mfma_f32_32x32x16_bf16(a, b, c, 0, 0, 0);
}
DEVI void gl_lds16(const void* g, void* l) {
  __builtin_amdgcn_global_load_lds((const __attribute__((address_space(1))) void*)g,
                                   (__attribute__((address_space(3))) void*)l,
                                   16, 0, 0);
}
DEVI unsigned cvtpk_bf16(float lo, float hi) {
  unsigned r;
  asm("v_cvt_pk_bf16_f32 %0, %1, %2" : "=v"(r) : "v"(lo), "v"(hi));
  return r;
}

// ---------------- elementwise helpers ----------------

__global__ void conv_bf16_k(const float* __restrict__ in, unsigned short* __restrict__ out, long n4) {
  long i = (long)blockIdx.x * blockDim.x + threadIdx.x;
  if (i >= n4) return;
  const float4 v = ((const float4*)in)[i];
  ushort4 o;
  o.x = f2bf(v.x); o.y = f2bf(v.y); o.z = f2bf(v.z); o.w = f2bf(v.w);
  ((ushort4*)out)[i] = o;
}

// one block per row of 1024; 256 threads * float4
__global__ void rmsnorm_k(const float* __restrict__ x, const float* __restrict__ wgt,
                          unsigned short* __restrict__ xn) {
  const int row = blockIdx.x;
  const int t = threadIdx.x;
  const float4 v = ((const float4*)(x + (long)row * 1024))[t];
  float ss = v.x * v.x + v.y * v.y + v.z * v.z + v.w * v.w;
#pragma unroll
  for (int m = 1; m < 64; m <<= 1) ss += __shfl_xor(ss, m, 64);
  __shared__ float red[4];
  if ((t & 63) == 0) red[t >> 6] = ss;
  __syncthreads();
  const float tot = red[0] + red[1] + red[2] + red[3];
  const float rms = rsqrtf(tot * (1.f / 1024.f) + 1e-5f);
  const float4 wv = ((const float4*)wgt)[t];
  ushort4 o;
  o.x = f2bf(v.x * rms * wv.x);
  o.y = f2bf(v.y * rms * wv.y);
  o.z = f2bf(v.z * rms * wv.z);
  o.w = f2bf(v.w * rms * wv.w);
  ((ushort4*)(xn + (long)row * 1024))[t] = o;
}

// cos/sin table: tab[0..65535]=cos(t*inv_freq[j]), tab[65536..]=sin  (t<2048, j<32)
__global__ void rope_tab_k(float* __restrict__ tab) {
  const int i = blockIdx.x * 256 + threadIdx.x;   // 65536 threads
  const int t = i >> 5, j = i & 31;
  const float inv = powf(10000.f, -(float)j * (1.f / 32.f));
  const float a = (float)t * inv;
  tab[i] = cosf(a);
  tab[65536 + i] = sinf(a);
}

// in-place RoPE on head-major [B*H][T=2048][64] bf16; scale folded (q: log2e/8)
__global__ void rope_apply_k(unsigned short* __restrict__ qk, const float* __restrict__ tab, float scale) {
  const long i = (long)blockIdx.x * 256 + threadIdx.x;  // B*H*T*32 threads
  const int j = (int)(i & 31);
  const long row = i >> 5;
  const int t = (int)(row & 2047);
  unsigned short* p = qk + row * 64;
  const float c = tab[t * 32 + j], s = tab[65536 + t * 32 + j];
  const float x1 = bf2f(p[j]), x2 = bf2f(p[j + 32]);
  p[j]      = f2bf((x1 * c - x2 * s) * scale);
  p[j + 32] = f2bf((x2 * c + x1 * s) * scale);
}

// ---------------- GEMM: C[M,N] = A[M,K] * B^T  (B stored [N][K] row-major) ----------------
template <int EPI>
__launch_bounds__(256, 2)
__global__ void gemm_bt_k(const unsigned short* __restrict__ A,
                          const unsigned short* __restrict__ Bw,
                          unsigned short* __restrict__ o_bf0,
                          unsigned short* __restrict__ o_bf1,
                          float* __restrict__ o_f32,
                          const float* __restrict__ resid,
                          int N, int K) {
  __shared__ unsigned short As[2][128 * 32];
  __shared__ unsigned short Bs[2][128 * 32];
  const int tix = threadIdx.x;
  const int w = tix >> 6, l = tix & 63;
  const int wr = w >> 1, wc = w & 1;
  const int lr = l & 15, lg = l >> 4;
  const long bm = blockIdx.y, bn = blockIdx.x;
  const long arow0 = bm * 128, brow0 = bn * 128;

  f32x4 acc[4][4] = {};

  const int r2 = tix >> 2, c2 = tix & 3;
  const int sw2 = c2 ^ (r2 & 3);

  auto stage = [&](int buf, int kt) {
    const long k0 = (long)kt * 32;
    const unsigned short* ga  = A  + (arow0 + r2) * K + k0 + sw2 * 8;
    const unsigned short* ga2 = A  + (arow0 + 64 + r2) * K + k0 + sw2 * 8;
    const unsigned short* gb  = Bw + (brow0 + r2) * K + k0 + sw2 * 8;
    const unsigned short* gb2 = Bw + (brow0 + 64 + r2) * K + k0 + sw2 * 8;
    char* la = (char*)&As[buf][0] + w * 1024;
    char* lb = (char*)&Bs[buf][0] + w * 1024;
    gl_lds16(ga,  la);
    gl_lds16(ga2, la + 4096);
    gl_lds16(gb,  lb);
    gl_lds16(gb2, lb + 4096);
  };

  auto lds_off = [&](int row, int chunk) { return row * 32 + ((chunk ^ (row & 3)) << 3); };

  auto compute = [&](int buf) {
    bf16x8 af[4], bv[4];
#pragma unroll
    for (int m = 0; m < 4; ++m)
      af[m] = *(const bf16x8*)&As[buf][lds_off(wr * 64 + m * 16 + lr, lg)];
#pragma unroll
    for (int n = 0; n < 4; ++n)
      bv[n] = *(const bf16x8*)&Bs[buf][lds_off(wc * 64 + n * 16 + lr, lg)];
#pragma unroll
    for (int m = 0; m < 4; ++m)
#pragma unroll
      for (int n = 0; n < 4; ++n)
        acc[m][n] = mfma16(af[m], bv[n], acc[m][n]);
  };

  const int nk = K >> 5;
  stage(0, 0);
  __syncthreads();
  int buf = 0;
#pragma unroll 1
  for (int kt = 0; kt < nk - 1; ++kt) {
    stage(buf ^ 1, kt + 1);
    compute(buf);
    __syncthreads();
    buf ^= 1;
  }
  compute(buf);

#pragma unroll
  for (int m = 0; m < 4; ++m) {
#pragma unroll
    for (int n = 0; n < 4; ++n) {
#pragma unroll
      for (int r = 0; r < 4; ++r) {
        const long grow = arow0 + wr * 64 + m * 16 + lg * 4 + r;  // token idx (b*2048+t)
        const long gcol = brow0 + wc * 64 + n * 16 + lr;          // feature
        const float v = acc[m][n][r];
        if constexpr (EPI == 0) {
          const long b = grow >> 11, t = grow & 2047;
          const long hh = gcol >> 6, d = gcol & 63;
          o_bf0[(((b * 16) + hh) * 2048 + t) * 64 + d] = f2bf(v);
        } else if constexpr (EPI == 1) {
          const long b = grow >> 11, t = grow & 2047;
          if (gcol < 1024) {
            const long hh = gcol >> 6, d = gcol & 63;
            o_bf0[(((b * 16) + hh) * 2048 + t) * 64 + d] = f2bf(v);
          } else {
            const long o2 = gcol - 1024;
            const long hh = o2 >> 6, d = o2 & 63;
            o_bf1[(((b * 16) + hh) * 64 + d) * 2048 + t] = f2bf(v);
          }
        } else {
          const long idx = grow * 1024 + gcol;
          o_f32[idx] = v + resid[idx];
        }
      }
    }
  }
  (void)N;
}

// ---------------- flash cross-attention, swapped-operand 32x32, no LDS ----------------
// 1D grid 1024 blocks: bh = blockIdx.x & 63 (XCD locality), qc = blockIdx.x >> 6.
// 4 waves/block, wave owns 32 q rows. Q pre-scaled by log2e/8 (exp2 domain).
// Q,K head-major [bh][2048][64]; V transposed [bh][64][2048].
__launch_bounds__(256, 4)
__global__ void attn_k(const unsigned short* __restrict__ Qh,
                       const unsigned short* __restrict__ Kh,
                       const unsigned short* __restrict__ Vt,
                       unsigned short* __restrict__ aout) {
  const int tix = threadIdx.x;
  const int w = tix >> 6, l = tix & 63;
  const int l31 = l & 31, hi = l >> 5;
  const int bid = blockIdx.x;
  const int bh = bid & 63, qc = bid >> 6;
  const long b = bh >> 4, h = bh & 15;
  const int q0 = qc * 128 + w * 32;
  const unsigned short* Qb = Qh + (long)bh * 2048 * 64;
  const unsigned short* Kb = Kh + (long)bh * 2048 * 64;
  const unsigned short* Vb = Vt + (long)bh * 64 * 2048;

  // Q B-frags: col=q=l31, k(d) = 16t + 8*hi + j
  bf16x8 qf[4];
#pragma unroll
  for (int t = 0; t < 4; ++t)
    qf[t] = *(const bf16x8*)(Qb + (long)(q0 + l31) * 64 + t * 16 + hi * 8);

  f32x16 o0 = {}, o1 = {};           // O^T frags: rows d in [0,32) / [32,64), col q = l31
  float m = -INFINITY, lsum = 0.f;

  const unsigned short* krow  = Kb + (long)l31 * 64 + hi * 8;         // + kv0*64 + 16t
  const unsigned short* vrow0 = Vb + (long)l31 * 2048 + hi * 8;       // + kv0 + 16t
  const unsigned short* vrow1 = Vb + (long)(32 + l31) * 2048 + hi * 8;

#pragma unroll 1
  for (int kt = 0; kt < 64; ++kt) {
    const long kv0 = (long)kt * 32;

    // K A-frags: row=kv=l31, k(d) = 16t + 8*hi + j
    bf16x8 kf0 = *(const bf16x8*)(krow + kv0 * 64);
    bf16x8 kf1 = *(const bf16x8*)(krow + kv0 * 64 + 16);
    bf16x8 kf2 = *(const bf16x8*)(krow + kv0 * 64 + 32);
    bf16x8 kf3 = *(const bf16x8*)(krow + kv0 * 64 + 48);

    f32x16 s = {};
    __builtin_amdgcn_s_setprio(1);
    s = mfma32(kf0, qf[0], s);
    s = mfma32(kf1, qf[1], s);
    s = mfma32(kf2, qf[2], s);
    s = mfma32(kf3, qf[3], s);
    __builtin_amdgcn_s_setprio(0);

    // V A-frags for PV (issue early; consumed after softmax)
    bf16x8 vf00 = *(const bf16x8*)(vrow0 + kv0);
    bf16x8 vf01 = *(const bf16x8*)(vrow0 + kv0 + 16);
    bf16x8 vf10 = *(const bf16x8*)(vrow1 + kv0);
    bf16x8 vf11 = *(const bf16x8*)(vrow1 + kv0 + 16);

    // lane-local online softmax (exp2 domain); lane owns q = q0+l31, kv slice by hi
    float tm = s[0];
#pragma unroll
    for (int i = 1; i < 16; ++i) tm = fmaxf(tm, s[i]);
    tm = fmaxf(tm, __shfl_xor(tm, 32, 64));
    const float mn = fmaxf(m, tm);
    const float al = exp2f(m - mn);
    m = mn;
    float p[16];
    float ts = 0.f;
#pragma unroll
    for (int i = 0; i < 16; ++i) { p[i] = exp2f(s[i] - mn); ts += p[i]; }
    ts += __shfl_xor(ts, 32, 64);
    lsum = lsum * al + ts;
#pragma unroll
    for (int i = 0; i < 16; ++i) { o0[i] *= al; o1[i] *= al; }

    // P relayout: C-frag rows kv=(r&3)+8*(r>>2)+4*hi  ->  B-frags k=kv=16t+8*hi+j
    unsigned W0 = cvtpk_bf16(p[0], p[1]),  W1 = cvtpk_bf16(p[2], p[3]);
    unsigned W2 = cvtpk_bf16(p[4], p[5]),  W3 = cvtpk_bf16(p[6], p[7]);
    unsigned W4 = cvtpk_bf16(p[8], p[9]),  W5 = cvtpk_bf16(p[10], p[11]);
    unsigned W6 = cvtpk_bf16(p[12], p[13]), W7 = cvtpk_bf16(p[14], p[15]);
    const unsigned W0p = __shfl_xor(W0, 32, 64), W1p = __shfl_xor(W1, 32, 64);
    const unsigned W2p = __shfl_xor(W2, 32, 64), W3p = __shfl_xor(W3, 32, 64);
    const unsigned W4p = __shfl_xor(W4, 32, 64), W5p = __shfl_xor(W5, 32, 64);
    const unsigned W6p = __shfl_xor(W6, 32, 64), W7p = __shfl_xor(W7, 32, 64);
    unsigned af0w[4], af1w[4];
    af0w[0] = hi ? W2p : W0;  af0w[1] = hi ? W3p : W1;
    af0w[2] = hi ? W2 : W0p;  af0w[3] = hi ? W3 : W1p;
    af1w[0] = hi ? W6p : W4;  af1w[1] = hi ? W7p : W5;
    af1w[2] = hi ? W6 : W4p;  af1w[3] = hi ? W7 : W5p;
    const bf16x8 af0 = *(const bf16x8*)af0w;
    const bf16x8 af1 = *(const bf16x8*)af1w;

    __builtin_amdgcn_s_setprio(1);
    o0 = mfma32(vf00, af0, o0);
    o0 = mfma32(vf01, af1, o0);
    o1 = mfma32(vf10, af0, o1);
    o1 = mfma32(vf11, af1, o1);
    __builtin_amdgcn_s_setprio(0);
  }

  const float inv = 1.f / lsum;
  unsigned short* orow = aout + ((b * 2048 + q0 + l31) * 1024 + h * 64);
#pragma unroll
  for (int rg = 0; rg < 4; ++rg) {
    ushort4 v0, v1;
    v0.x = f2bf(o0[rg * 4 + 0] * inv); v0.y = f2bf(o0[rg * 4 + 1] * inv);
    v0.z = f2bf(o0[rg * 4 + 2] * inv); v0.w = f2bf(o0[rg * 4 + 3] * inv);
    v1.x = f2bf(o1[rg * 4 + 0] * inv); v1.y = f2bf(o1[rg * 4 + 1] * inv);
    v1.z = f2bf(o1[rg * 4 + 2] * inv); v1.w = f2bf(o1[rg * 4 + 3] * inv);
    *(ushort4*)(orow + rg * 8 + hi * 4)      = v0;   // d = rg*8 + 4*hi + i
    *(ushort4*)(orow + 32 + rg * 8 + hi * 4) = v1;   // d = 32 + ...
  }
}

// ---------------- launch ----------------

extern "C" void kernel_launch(void* const* d_in, const int* in_sizes, int n_in,
                              void* d_out, int out_size, void* d_ws, size_t ws_size,
                              hipStream_t stream) {
  const float* x   = (const float*)d_in[0];
  const float* enc = (const float*)d_in[1];
  const float* nw  = (const float*)d_in[2];
  const float* Wq  = (const float*)d_in[3];
  const float* Wkv = (const float*)d_in[4];
  const float* Wo  = (const float*)d_in[5];
  float* out = (float*)d_out;
  char* ws = (char*)d_ws;
  const long MB = 1024 * 1024;
  unsigned short* xn   = (unsigned short*)(ws);            // 16MB (reused as attn_out)
  unsigned short* encb = (unsigned short*)(ws + 16 * MB);  // 16MB
  unsigned short* wqb  = (unsigned short*)(ws + 32 * MB);  // 2MB
  unsigned short* wkvb = (unsigned short*)(ws + 34 * MB);  // 4MB
  unsigned short* wob  = (unsigned short*)(ws + 38 * MB);  // 2MB
  unsigned short* Qh   = (unsigned short*)(ws + 40 * MB);  // 16MB
  unsigned short* Kh   = (unsigned short*)(ws + 56 * MB);  // 16MB
  unsigned short* Vt   = (unsigned short*)(ws + 72 * MB);  // 16MB
  float* tab           = (float*)(ws + 88 * MB);           // 512KB
  unsigned short* aout = xn;

  conv_bf16_k<<<1024, 256, 0, stream>>>(Wq, wqb, 262144);
  conv_bf16_k<<<2048, 256, 0, stream>>>(Wkv, wkvb, 524288);
  conv_bf16_k<<<1024, 256, 0, stream>>>(Wo, wob, 262144);
  conv_bf16_k<<<8192, 256, 0, stream>>>(enc, encb, 2097152);
  rmsnorm_k<<<8192, 256, 0, stream>>>(x, nw, xn);
  rope_tab_k<<<256, 256, 0, stream>>>(tab);
  gemm_bt_k<0><<<dim3(8, 64), 256, 0, stream>>>(xn, wqb, Qh, nullptr, nullptr, nullptr, 1024, 1024);
  gemm_bt_k<1><<<dim3(16, 64), 256, 0, stream>>>(encb, wkvb, Kh, Vt, nullptr, nullptr, 2048, 1024);
  // Q scale = (1/8) * log2(e)  -> scores land in exp2 domain
  rope_apply_k<<<16384, 256, 0, stream>>>(Qh, tab, 0.18033688f);
  rope_apply_k<<<16384, 256, 0, stream>>>(Kh, tab, 1.0f);
  attn_k<<<1024, 256, 0, stream>>>(Qh, Kh, Vt, aout);
  gemm_bt_k<2><<<dim3(8, 64), 256, 0, stream>>>(aout, wob, nullptr, nullptr, out, x, 1024, 1024);
  (void)in_sizes; (void)n_in; (void)out_size; (void)ws_size;
}

// Round 5
// 512.168 us; speedup vs baseline: 1.1438x; 1.0012x over previous
//
#include <hip/hip_runtime.h>
#include <cstdint>

// FlashCrossAttention round 5: R3 structure with the cross-half max-combine
// fix (tm = fmax(tm, other_half) instead of tm = other_half).
// B=4, Td=Te=2048, D=1024, H=16, hd=64.

#define DEVI __device__ __forceinline__

typedef float f32x4 __attribute__((ext_vector_type(4)));
typedef float f32x16 __attribute__((ext_vector_type(16)));
typedef __bf16 bf16x8 __attribute__((ext_vector_type(8)));
typedef unsigned u32x2 __attribute__((ext_vector_type(2)));

DEVI unsigned short f2bf(float f) {
  union { float f; unsigned u; } v; v.f = f;
  unsigned r = v.u + 0x7FFFu + ((v.u >> 16) & 1u);   // RTNE
  return (unsigned short)(r >> 16);
}
DEVI float bf2f(unsigned short h) {
  union { unsigned u; float f; } v; v.u = ((unsigned)h) << 16;
  return v.f;
}
DEVI f32x4 mfma16(bf16x8 a, bf16x8 b, f32x4 c) {
  return __builtin_amdgcn_mfma_f32_16x16x32_bf16(a, b, c, 0, 0, 0);
}
DEVI f32x16 mfma32(bf16x8 a, bf16x8 b, f32x16 c) {
  return __builtin_amdgcn_mfma_f32_32x32x16_bf16(a, b, c, 0, 0, 0);
}
DEVI void gl_lds16(const void* g, void* l) {
  __builtin_amdgcn_global_load_lds((const __attribute__((address_space(1))) void*)g,
                                   (__attribute__((address_space(3))) void*)l,
                                   16, 0, 0);
}
DEVI unsigned cvtpk_bf16(float lo, float hi) {
  unsigned r;
  asm("v_cvt_pk_bf16_f32 %0, %1, %2" : "=v"(r) : "v"(lo), "v"(hi));
  return r;
}
// cross-half (lane ^ 32) fetch via permlane32_swap: returns other half's value
DEVI float xhalf(float x, int hi) {
  union { float f; unsigned u; } a; a.f = x;
  u32x2 r = __builtin_amdgcn_permlane32_swap(a.u, a.u, false, false);
  union { unsigned u; float f; } o; o.u = hi ? r.x : r.y;
  return o.f;
}

// ---------------- elementwise helpers ----------------

__global__ void conv_bf16_k(const float* __restrict__ in, unsigned short* __restrict__ out, long n4) {
  long i = (long)blockIdx.x * blockDim.x + threadIdx.x;
  if (i >= n4) return;
  const float4 v = ((const float4*)in)[i];
  ushort4 o;
  o.x = f2bf(v.x); o.y = f2bf(v.y); o.z = f2bf(v.z); o.w = f2bf(v.w);
  ((ushort4*)out)[i] = o;
}

__global__ void rmsnorm_k(const float* __restrict__ x, const float* __restrict__ wgt,
                          unsigned short* __restrict__ xn) {
  const int row = blockIdx.x;
  const int t = threadIdx.x;
  const float4 v = ((const float4*)(x + (long)row * 1024))[t];
  float ss = v.x * v.x + v.y * v.y + v.z * v.z + v.w * v.w;
#pragma unroll
  for (int m = 1; m < 64; m <<= 1) ss += __shfl_xor(ss, m, 64);
  __shared__ float red[4];
  if ((t & 63) == 0) red[t >> 6] = ss;
  __syncthreads();
  const float tot = red[0] + red[1] + red[2] + red[3];
  const float rms = rsqrtf(tot * (1.f / 1024.f) + 1e-5f);
  const float4 wv = ((const float4*)wgt)[t];
  ushort4 o;
  o.x = f2bf(v.x * rms * wv.x);
  o.y = f2bf(v.y * rms * wv.y);
  o.z = f2bf(v.z * rms * wv.z);
  o.w = f2bf(v.w * rms * wv.w);
  ((ushort4*)(xn + (long)row * 1024))[t] = o;
}

__global__ void rope_tab_k(float* __restrict__ tab) {
  const int i = blockIdx.x * 256 + threadIdx.x;   // 65536 threads
  const int t = i >> 5, j = i & 31;
  const float inv = powf(10000.f, -(float)j * (1.f / 32.f));
  const float a = (float)t * inv;
  tab[i] = cosf(a);
  tab[65536 + i] = sinf(a);
}

__global__ void rope_apply_k(unsigned short* __restrict__ qk, const float* __restrict__ tab, float scale) {
  const long i = (long)blockIdx.x * 256 + threadIdx.x;  // B*H*T*32 threads
  const int j = (int)(i & 31);
  const long row = i >> 5;
  const int t = (int)(row & 2047);
  unsigned short* p = qk + row * 64;
  const float c = tab[t * 32 + j], s = tab[65536 + t * 32 + j];
  const float x1 = bf2f(p[j]), x2 = bf2f(p[j + 32]);
  p[j]      = f2bf((x1 * c - x2 * s) * scale);
  p[j + 32] = f2bf((x2 * c + x1 * s) * scale);
}

// ---------------- GEMM: C[M,N] = A[M,K] * B^T ----------------
template <int EPI>
__launch_bounds__(256, 2)
__global__ void gemm_bt_k(const unsigned short* __restrict__ A,
                          const unsigned short* __restrict__ Bw,
                          unsigned short* __restrict__ o_bf0,
                          unsigned short* __restrict__ o_bf1,
                          float* __restrict__ o_f32,
                          const float* __restrict__ resid,
                          int N, int K) {
  __shared__ unsigned short As[2][128 * 32];
  __shared__ unsigned short Bs[2][128 * 32];
  const int tix = threadIdx.x;
  const int w = tix >> 6, l = tix & 63;
  const int wr = w >> 1, wc = w & 1;
  const int lr = l & 15, lg = l >> 4;
  const long bm = blockIdx.y, bn = blockIdx.x;
  const long arow0 = bm * 128, brow0 = bn * 128;

  f32x4 acc[4][4] = {};

  const int r2 = tix >> 2, c2 = tix & 3;
  const int sw2 = c2 ^ (r2 & 3);

  auto stage = [&](int buf, int kt) {
    const long k0 = (long)kt * 32;
    const unsigned short* ga  = A  + (arow0 + r2) * K + k0 + sw2 * 8;
    const unsigned short* ga2 = A  + (arow0 + 64 + r2) * K + k0 + sw2 * 8;
    const unsigned short* gb  = Bw + (brow0 + r2) * K + k0 + sw2 * 8;
    const unsigned short* gb2 = Bw + (brow0 + 64 + r2) * K + k0 + sw2 * 8;
    char* la = (char*)&As[buf][0] + w * 1024;
    char* lb = (char*)&Bs[buf][0] + w * 1024;
    gl_lds16(ga,  la);
    gl_lds16(ga2, la + 4096);
    gl_lds16(gb,  lb);
    gl_lds16(gb2, lb + 4096);
  };

  auto lds_off = [&](int row, int chunk) { return row * 32 + ((chunk ^ (row & 3)) << 3); };

  auto compute = [&](int buf) {
    bf16x8 af[4], bv[4];
#pragma unroll
    for (int m = 0; m < 4; ++m)
      af[m] = *(const bf16x8*)&As[buf][lds_off(wr * 64 + m * 16 + lr, lg)];
#pragma unroll
    for (int n = 0; n < 4; ++n)
      bv[n] = *(const bf16x8*)&Bs[buf][lds_off(wc * 64 + n * 16 + lr, lg)];
#pragma unroll
    for (int m = 0; m < 4; ++m)
#pragma unroll
      for (int n = 0; n < 4; ++n)
        acc[m][n] = mfma16(af[m], bv[n], acc[m][n]);
  };

  const int nk = K >> 5;
  stage(0, 0);
  __syncthreads();
  int buf = 0;
#pragma unroll 1
  for (int kt = 0; kt < nk - 1; ++kt) {
    stage(buf ^ 1, kt + 1);
    compute(buf);
    __syncthreads();
    buf ^= 1;
  }
  compute(buf);

#pragma unroll
  for (int m = 0; m < 4; ++m) {
#pragma unroll
    for (int n = 0; n < 4; ++n) {
#pragma unroll
      for (int r = 0; r < 4; ++r) {
        const long grow = arow0 + wr * 64 + m * 16 + lg * 4 + r;  // token idx (b*2048+t)
        const long gcol = brow0 + wc * 64 + n * 16 + lr;          // feature
        const float v = acc[m][n][r];
        if constexpr (EPI == 0) {
          const long b = grow >> 11, t = grow & 2047;
          const long hh = gcol >> 6, d = gcol & 63;
          o_bf0[(((b * 16) + hh) * 2048 + t) * 64 + d] = f2bf(v);
        } else if constexpr (EPI == 1) {
          const long b = grow >> 11, t = grow & 2047;
          if (gcol < 1024) {
            const long hh = gcol >> 6, d = gcol & 63;
            o_bf0[(((b * 16) + hh) * 2048 + t) * 64 + d] = f2bf(v);
          } else {
            const long o2 = gcol - 1024;
            const long hh = o2 >> 6, d = o2 & 63;
            o_bf1[(((b * 16) + hh) * 64 + d) * 2048 + t] = f2bf(v);
          }
        } else {
          const long idx = grow * 1024 + gcol;
          o_f32[idx] = v + resid[idx];
        }
      }
    }
  }
  (void)N;
}

// ---------------- flash cross-attention ----------------
// 1D grid 1024 blocks: bh = blockIdx.x & 63 (XCD locality), qc = blockIdx.x >> 6.
// 4 waves/block, wave owns 32 q rows. Q pre-scaled by log2e/8 (exp2 domain).
__launch_bounds__(256, 3)
__global__ void attn_k(const unsigned short* __restrict__ Qh,
                       const unsigned short* __restrict__ Kh,
                       const unsigned short* __restrict__ Vt,
                       unsigned short* __restrict__ aout) {
  const int tix = threadIdx.x;
  const int w = tix >> 6, l = tix & 63;
  const int l31 = l & 31, hi = l >> 5;
  const int bid = blockIdx.x;
  const int bh = bid & 63, qc = bid >> 6;
  const long b = bh >> 4, h = bh & 15;
  const int q0 = qc * 128 + w * 32;
  const unsigned short* Qb = Qh + (long)bh * 2048 * 64;
  const unsigned short* Kb = Kh + (long)bh * 2048 * 64;
  const unsigned short* Vb = Vt + (long)bh * 64 * 2048;

  bf16x8 qf[4];
#pragma unroll
  for (int t = 0; t < 4; ++t)
    qf[t] = *(const bf16x8*)(Qb + (long)(q0 + l31) * 64 + t * 16 + hi * 8);

  f32x16 o0 = {}, o1 = {};           // O^T frags: rows d in [0,32)/[32,64), col q=l31
  float m = -INFINITY, lsum = 0.f;

  const unsigned short* krow  = Kb + (long)l31 * 64 + hi * 8;
  const unsigned short* vrow0 = Vb + (long)l31 * 2048 + hi * 8;
  const unsigned short* vrow1 = Vb + (long)(32 + l31) * 2048 + hi * 8;

  bf16x8 kA[4], vA[4], kB[4], vB[4];

  auto loadKV = [&](int kt, bf16x8* kf, bf16x8* vf) {
    const long kv0 = (long)kt * 32;
    kf[0] = *(const bf16x8*)(krow + kv0 * 64);
    kf[1] = *(const bf16x8*)(krow + kv0 * 64 + 16);
    kf[2] = *(const bf16x8*)(krow + kv0 * 64 + 32);
    kf[3] = *(const bf16x8*)(krow + kv0 * 64 + 48);
    vf[0] = *(const bf16x8*)(vrow0 + kv0);
    vf[1] = *(const bf16x8*)(vrow0 + kv0 + 16);
    vf[2] = *(const bf16x8*)(vrow1 + kv0);
    vf[3] = *(const bf16x8*)(vrow1 + kv0 + 16);
  };

  auto process = [&](const bf16x8* kf, const bf16x8* vf) {
    f32x16 s = {};
    __builtin_amdgcn_s_setprio(1);
    s = mfma32(kf[0], qf[0], s);
    s = mfma32(kf[1], qf[1], s);
    s = mfma32(kf[2], qf[2], s);
    s = mfma32(kf[3], qf[3], s);
    __builtin_amdgcn_s_setprio(0);

    // tree max over 16 (v_max3), then combine with other half via permlane
    float m0 = fmaxf(fmaxf(s[0], s[1]), s[2]);
    float m1 = fmaxf(fmaxf(s[3], s[4]), s[5]);
    float m2 = fmaxf(fmaxf(s[6], s[7]), s[8]);
    float m3 = fmaxf(fmaxf(s[9], s[10]), s[11]);
    float m4 = fmaxf(fmaxf(s[12], s[13]), s[14]);
    float tm = fmaxf(fmaxf(fmaxf(m0, m1), m2), fmaxf(fmaxf(m3, m4), s[15]));
    tm = fmaxf(tm, xhalf(tm, hi));   // FIX: combine, don't replace

    // defer-max (T13): only rescale when the running max grows by > 8 (log2 domain)
    if (__any(tm > m + 8.f)) {
      const float mn = fmaxf(m, tm);
      const float al = exp2f(m - mn);
      m = mn;
      lsum *= al;
#pragma unroll
      for (int i = 0; i < 16; ++i) { o0[i] *= al; o1[i] *= al; }
    }

    // p in-place (exp2 domain)
#pragma unroll
    for (int i = 0; i < 16; ++i) s[i] = exp2f(s[i] - m);
    // tree sum + cross-half
    float t0 = (s[0] + s[1]) + (s[2] + s[3]);
    float t1 = (s[4] + s[5]) + (s[6] + s[7]);
    float t2 = (s[8] + s[9]) + (s[10] + s[11]);
    float t3 = (s[12] + s[13]) + (s[14] + s[15]);
    float ts = (t0 + t1) + (t2 + t3);
    lsum += ts + xhalf(ts, hi);

    // P relayout: C-frag -> B-frags via cvt_pk + permlane32_swap
    unsigned W0 = cvtpk_bf16(s[0], s[1]),   W1 = cvtpk_bf16(s[2], s[3]);
    unsigned W2 = cvtpk_bf16(s[4], s[5]),   W3 = cvtpk_bf16(s[6], s[7]);
    unsigned W4 = cvtpk_bf16(s[8], s[9]),   W5 = cvtpk_bf16(s[10], s[11]);
    unsigned W6 = cvtpk_bf16(s[12], s[13]), W7 = cvtpk_bf16(s[14], s[15]);
    const u32x2 r02 = __builtin_amdgcn_permlane32_swap(W0, W2, false, false);
    const u32x2 r13 = __builtin_amdgcn_permlane32_swap(W1, W3, false, false);
    const u32x2 r46 = __builtin_amdgcn_permlane32_swap(W4, W6, false, false);
    const u32x2 r57 = __builtin_amdgcn_permlane32_swap(W5, W7, false, false);
    unsigned af0w[4] = { r02.x, r13.x, r02.y, r13.y };
    unsigned af1w[4] = { r46.x, r57.x, r46.y, r57.y };
    const bf16x8 af0 = *(const bf16x8*)af0w;
    const bf16x8 af1 = *(const bf16x8*)af1w;

    __builtin_amdgcn_s_setprio(1);
    o0 = mfma32(vf[0], af0, o0);
    o0 = mfma32(vf[1], af1, o0);
    o1 = mfma32(vf[2], af0, o1);
    o1 = mfma32(vf[3], af1, o1);
    __builtin_amdgcn_s_setprio(0);
  };

  loadKV(0, kA, vA);
#pragma unroll 1
  for (int kt = 0; kt < 62; kt += 2) {
    loadKV(kt + 1, kB, vB);
    process(kA, vA);
    loadKV(kt + 2, kA, vA);
    process(kB, vB);
  }
  loadKV(63, kB, vB);
  process(kA, vA);   // tile 62
  process(kB, vB);   // tile 63

  const float inv = 1.f / lsum;
  unsigned short* orow = aout + ((b * 2048 + q0 + l31) * 1024 + h * 64);
#pragma unroll
  for (int rg = 0; rg < 4; ++rg) {
    ushort4 v0, v1;
    v0.x = f2bf(o0[rg * 4 + 0] * inv); v0.y = f2bf(o0[rg * 4 + 1] * inv);
    v0.z = f2bf(o0[rg * 4 + 2] * inv); v0.w = f2bf(o0[rg * 4 + 3] * inv);
    v1.x = f2bf(o1[rg * 4 + 0] * inv); v1.y = f2bf(o1[rg * 4 + 1] * inv);
    v1.z = f2bf(o1[rg * 4 + 2] * inv); v1.w = f2bf(o1[rg * 4 + 3] * inv);
    *(ushort4*)(orow + rg * 8 + hi * 4)      = v0;
    *(ushort4*)(orow + 32 + rg * 8 + hi * 4) = v1;
  }
}

// ---------------- launch ----------------

extern "C" void kernel_launch(void* const* d_in, const int* in_sizes, int n_in,
                              void* d_out, int out_size, void* d_ws, size_t ws_size,
                              hipStream_t stream) {
  const float* x   = (const float*)d_in[0];
  const float* enc = (const float*)d_in[1];
  const float* nw  = (const float*)d_in[2];
  const float* Wq  = (const float*)d_in[3];
  const float* Wkv = (const float*)d_in[4];
  const float* Wo  = (const float*)d_in[5];
  float* out = (float*)d_out;
  char* ws = (char*)d_ws;
  const long MB = 1024 * 1024;
  unsigned short* xn   = (unsigned short*)(ws);            // 16MB (reused as attn_out)
  unsigned short* encb = (unsigned short*)(ws + 16 * MB);  // 16MB
  unsigned short* wqb  = (unsigned short*)(ws + 32 * MB);  // 2MB
  unsigned short* wkvb = (unsigned short*)(ws + 34 * MB);  // 4MB
  unsigned short* wob  = (unsigned short*)(ws + 38 * MB);  // 2MB
  unsigned short* Qh   = (unsigned short*)(ws + 40 * MB);  // 16MB
  unsigned short* Kh   = (unsigned short*)(ws + 56 * MB);  // 16MB
  unsigned short* Vt   = (unsigned short*)(ws + 72 * MB);  // 16MB
  float* tab           = (float*)(ws + 88 * MB);           // 512KB
  unsigned short* aout = xn;

  conv_bf16_k<<<1024, 256, 0, stream>>>(Wq, wqb, 262144);
  conv_bf16_k<<<2048, 256, 0, stream>>>(Wkv, wkvb, 524288);
  conv_bf16_k<<<1024, 256, 0, stream>>>(Wo, wob, 262144);
  conv_bf16_k<<<8192, 256, 0, stream>>>(enc, encb, 2097152);
  rmsnorm_k<<<8192, 256, 0, stream>>>(x, nw, xn);
  rope_tab_k<<<256, 256, 0, stream>>>(tab);
  gemm_bt_k<0><<<dim3(8, 64), 256, 0, stream>>>(xn, wqb, Qh, nullptr, nullptr, nullptr, 1024, 1024);
  gemm_bt_k<1><<<dim3(16, 64), 256, 0, stream>>>(encb, wkvb, Kh, Vt, nullptr, nullptr, 2048, 1024);
  // Q scale = (1/8) * log2(e)  -> scores land in exp2 domain
  rope_apply_k<<<16384, 256, 0, stream>>>(Qh, tab, 0.18033688f);
  rope_apply_k<<<16384, 256, 0, stream>>>(Kh, tab, 1.0f);
  attn_k<<<1024, 256, 0, stream>>>(Qh, Kh, Vt, aout);
  gemm_bt_k<2><<<dim3(8, 64), 256, 0, stream>>>(aout, wob, nullptr, nullptr, out, x, 1024, 1024);
  (void)in_sizes; (void)n_in; (void)out_size; (void)ws_size;
}

// Round 6
// 359.588 us; speedup vs baseline: 1.6291x; 1.4243x over previous
//
#include <hip/hip_runtime.h>
#include <cstdint>

// FlashCrossAttention round 6: fragment-ordered Q/K/V layouts written by the
// projection epilogues (RoPE fused there), LDS-staged coalesced attention.
// B=4, Td=Te=2048, D=1024, H=16, hd=64.

#define DEVI __device__ __forceinline__

typedef float f32x4 __attribute__((ext_vector_type(4)));
typedef float f32x16 __attribute__((ext_vector_type(16)));
typedef __bf16 bf16x8 __attribute__((ext_vector_type(8)));
typedef unsigned u32x2 __attribute__((ext_vector_type(2)));

DEVI unsigned short f2bf(float f) {
  union { float f; unsigned u; } v; v.f = f;
  unsigned r = v.u + 0x7FFFu + ((v.u >> 16) & 1u);   // RTNE
  return (unsigned short)(r >> 16);
}
DEVI f32x4 mfma16(bf16x8 a, bf16x8 b, f32x4 c) {
  return __builtin_amdgcn_mfma_f32_16x16x32_bf16(a, b, c, 0, 0, 0);
}
DEVI f32x16 mfma32(bf16x8 a, bf16x8 b, f32x16 c) {
  return __builtin_amdgcn_mfma_f32_32x32x16_bf16(a, b, c, 0, 0, 0);
}
DEVI void gl_lds16(const void* g, void* l) {
  __builtin_amdgcn_global_load_lds((const __attribute__((address_space(1))) void*)g,
                                   (__attribute__((address_space(3))) void*)l,
                                   16, 0, 0);
}
DEVI unsigned cvtpk_bf16(float lo, float hi) {
  unsigned r;
  asm("v_cvt_pk_bf16_f32 %0, %1, %2" : "=v"(r) : "v"(lo), "v"(hi));
  return r;
}
// cross-half (lane ^ 32) fetch via permlane32_swap
DEVI float xhalf(float x, int hi) {
  union { float f; unsigned u; } a; a.f = x;
  u32x2 r = __builtin_amdgcn_permlane32_swap(a.u, a.u, false, false);
  union { unsigned u; float f; } o; o.u = hi ? r.x : r.y;
  return o.f;
}

// ---------------- elementwise helpers ----------------

__global__ void conv_bf16_k(const float* __restrict__ in, unsigned short* __restrict__ out, long n4) {
  long i = (long)blockIdx.x * blockDim.x + threadIdx.x;
  if (i >= n4) return;
  const float4 v = ((const float4*)in)[i];
  ushort4 o;
  o.x = f2bf(v.x); o.y = f2bf(v.y); o.z = f2bf(v.z); o.w = f2bf(v.w);
  ((ushort4*)out)[i] = o;
}

__global__ void rmsnorm_k(const float* __restrict__ x, const float* __restrict__ wgt,
                          unsigned short* __restrict__ xn) {
  const int row = blockIdx.x;
  const int t = threadIdx.x;
  const float4 v = ((const float4*)(x + (long)row * 1024))[t];
  float ss = v.x * v.x + v.y * v.y + v.z * v.z + v.w * v.w;
#pragma unroll
  for (int m = 1; m < 64; m <<= 1) ss += __shfl_xor(ss, m, 64);
  __shared__ float red[4];
  if ((t & 63) == 0) red[t >> 6] = ss;
  __syncthreads();
  const float tot = red[0] + red[1] + red[2] + red[3];
  const float rms = rsqrtf(tot * (1.f / 1024.f) + 1e-5f);
  const float4 wv = ((const float4*)wgt)[t];
  ushort4 o;
  o.x = f2bf(v.x * rms * wv.x);
  o.y = f2bf(v.y * rms * wv.y);
  o.z = f2bf(v.z * rms * wv.z);
  o.w = f2bf(v.w * rms * wv.w);
  ((ushort4*)(xn + (long)row * 1024))[t] = o;
}

// cos/sin table layout [j][t]: tab[j*2048 + t] = cos(t*invfreq[j]); +65536 sin
__global__ void rope_tab_k(float* __restrict__ tab) {
  const int i = blockIdx.x * 256 + threadIdx.x;   // 65536 threads
  const int j = i >> 11, t = i & 2047;
  const float inv = powf(10000.f, -(float)j * (1.f / 32.f));
  const float a = (float)t * inv;
  tab[i] = cosf(a);
  tab[65536 + i] = sinf(a);
}

// ---------------- GEMM: C[M,N] = A[M,K] * B^T ----------------
// EPI 0: RoPE (scale scl) + scatter to Q fragment layout (o_bf0)
// EPI 1: cols<1024: RoPE + scatter to K fragment layout (o_bf0)
//        cols>=1024: scatter to V fragment layout (o_bf1)
// EPI 2: fp32 out = acc + resid
// Fragment layouts (ushort idx), bh = b*16+h:
//  Q/K: (((bh*64 + t32)*4 + tf)*64 + hi*32 + (tok&31))*8 + j  with d = tf*16+hi*8+j
//  V:   (((bh*64 + kt)*4 + vi)*64 + hi*32 + (d&31))*8 + jj    with kv5 = (vi&1)*16+hi*8+jj, vi>=2 <-> d>=32
template <int EPI>
__launch_bounds__(256, 2)
__global__ void gemm_bt_k(const unsigned short* __restrict__ A,
                          const unsigned short* __restrict__ Bw,
                          unsigned short* __restrict__ o_bf0,
                          unsigned short* __restrict__ o_bf1,
                          float* __restrict__ o_f32,
                          const float* __restrict__ resid,
                          const float* __restrict__ cosT,
                          const float* __restrict__ sinT,
                          float scl, int N, int K) {
  __shared__ unsigned short As[2][128 * 32];
  __shared__ unsigned short Bs[2][128 * 32];
  const int tix = threadIdx.x;
  const int w = tix >> 6, l = tix & 63;
  const int wr = w >> 1, wc = w & 1;
  const int lr = l & 15, lg = l >> 4;
  const long bm = blockIdx.y, bn = blockIdx.x;
  const long arow0 = bm * 128, brow0 = bn * 128;

  f32x4 acc[4][4] = {};

  const int r2 = tix >> 2, c2 = tix & 3;
  const int sw2 = c2 ^ (r2 & 3);

  auto stage = [&](int buf, int kt) {
    const long k0 = (long)kt * 32;
    const unsigned short* ga  = A  + (arow0 + r2) * K + k0 + sw2 * 8;
    const unsigned short* ga2 = A  + (arow0 + 64 + r2) * K + k0 + sw2 * 8;
    const unsigned short* gb  = Bw + (brow0 + r2) * K + k0 + sw2 * 8;
    const unsigned short* gb2 = Bw + (brow0 + 64 + r2) * K + k0 + sw2 * 8;
    char* la = (char*)&As[buf][0] + w * 1024;
    char* lb = (char*)&Bs[buf][0] + w * 1024;
    gl_lds16(ga,  la);
    gl_lds16(ga2, la + 4096);
    gl_lds16(gb,  lb);
    gl_lds16(gb2, lb + 4096);
  };

  auto lds_off = [&](int row, int chunk) { return row * 32 + ((chunk ^ (row & 3)) << 3); };

  auto compute = [&](int buf) {
    bf16x8 af[4], bv[4];
#pragma unroll
    for (int m = 0; m < 4; ++m)
      af[m] = *(const bf16x8*)&As[buf][lds_off(wr * 64 + m * 16 + lr, lg)];
#pragma unroll
    for (int n = 0; n < 4; ++n)
      bv[n] = *(const bf16x8*)&Bs[buf][lds_off(wc * 64 + n * 16 + lr, lg)];
#pragma unroll
    for (int m = 0; m < 4; ++m)
#pragma unroll
      for (int n = 0; n < 4; ++n)
        acc[m][n] = mfma16(af[m], bv[n], acc[m][n]);
  };

  const int nk = K >> 5;
  stage(0, 0);
  __syncthreads();
  int buf = 0;
#pragma unroll 1
  for (int kt = 0; kt < nk - 1; ++kt) {
    stage(buf ^ 1, kt + 1);
    compute(buf);
    __syncthreads();
    buf ^= 1;
  }
  compute(buf);

  if constexpr (EPI == 2) {
#pragma unroll
    for (int m = 0; m < 4; ++m)
#pragma unroll
      for (int n = 0; n < 4; ++n)
#pragma unroll
        for (int r = 0; r < 4; ++r) {
          const long grow = arow0 + wr * 64 + m * 16 + lg * 4 + r;
          const long gcol = brow0 + wc * 64 + n * 16 + lr;
          const long idx = grow * 1024 + gcol;
          o_f32[idx] = acc[m][n][r] + resid[idx];
        }
    return;
  }

  const long b = arow0 >> 11;                    // batch (tile fits one batch block)
  const bool isV = (EPI == 1) && (brow0 >= 1024);
  const long colbase = isV ? (brow0 - 1024 + wc * 64) : (brow0 + wc * 64);
  const long hh = (colbase >> 6) & 15;
  const long bh = b * 16 + hh;

#pragma unroll
  for (int m = 0; m < 4; ++m) {
    const long tt0 = (arow0 + wr * 64 + m * 16 + lg * 4) & 2047;
    if (!isV) {
      // RoPE path (Q or K): d in {lr, 16+lr, 32+lr, 48+lr}; pairs (lr,32+lr),(16+lr,48+lr)
      const float4 c0 = *(const float4*)(cosT + (long)lr * 2048 + tt0);
      const float4 s0 = *(const float4*)(sinT + (long)lr * 2048 + tt0);
      const float4 c1 = *(const float4*)(cosT + (long)(16 + lr) * 2048 + tt0);
      const float4 s1 = *(const float4*)(sinT + (long)(16 + lr) * 2048 + tt0);
      const int hi_ = (lr >> 3) & 1, j_ = lr & 7;
#pragma unroll
      for (int r = 0; r < 4; ++r) {
        const long tt = tt0 + r;
        const long base = (((bh * 64 + (tt >> 5)) * 4 + 0) * 64 + hi_ * 32 + (tt & 31)) * 8 + j_;
        const float a0 = acc[m][0][r], a1 = acc[m][1][r], a2 = acc[m][2][r], a3 = acc[m][3][r];
        const float cc0 = ((const float*)&c0)[r], ss0 = ((const float*)&s0)[r];
        const float cc1 = ((const float*)&c1)[r], ss1 = ((const float*)&s1)[r];
        o_bf0[base]        = f2bf((a0 * cc0 - a2 * ss0) * scl);
        o_bf0[base + 512]  = f2bf((a1 * cc1 - a3 * ss1) * scl);
        o_bf0[base + 1024] = f2bf((a2 * cc0 + a0 * ss0) * scl);
        o_bf0[base + 1536] = f2bf((a3 * cc1 + a1 * ss1) * scl);
      }
    } else {
      // V path: token tt is the kv position; d in {lr,16+lr,32+lr,48+lr}
#pragma unroll
      for (int r = 0; r < 4; ++r) {
        const long tt = tt0 + r;
        const long kt = tt >> 5, kv5 = tt & 31;
        const long viL = kv5 >> 4, hi_ = (kv5 >> 3) & 1, jj = kv5 & 7;
        const long base = (((bh * 64 + kt) * 4 + viL) * 64 + hi_ * 32 + lr) * 8 + jj;
        o_bf1[base]              = f2bf(acc[m][0][r]);
        o_bf1[base + 128]        = f2bf(acc[m][1][r]);
        o_bf1[base + 1024]       = f2bf(acc[m][2][r]);
        o_bf1[base + 1024 + 128] = f2bf(acc[m][3][r]);
      }
    }
  }
  (void)N;
}

// ---------------- flash cross-attention ----------------
// 1D grid 1024 blocks: bh = blockIdx.x & 63 (XCD locality), qc = blockIdx.x >> 6.
// 4 waves/block, wave owns 32 q rows; block shares LDS-staged K/V tiles (32 kv).
// Q pre-scaled by log2e/8 (exp2 domain). All global loads fragment-ordered, coalesced.
__launch_bounds__(256, 4)
__global__ void attn_k(const unsigned short* __restrict__ Qf,
                       const unsigned short* __restrict__ Kf,
                       const unsigned short* __restrict__ Vf,
                       unsigned short* __restrict__ aout) {
  __shared__ unsigned short KLDS[2][2048];   // 4KB per buffer, fragment order
  __shared__ unsigned short VLDS[2][2048];
  const int tix = threadIdx.x;
  const int w = tix >> 6, l = tix & 63;
  const int l31 = l & 31, hi = l >> 5;
  const int bid = blockIdx.x;
  const int bh = bid & 63, qc = bid >> 6;
  const long b = bh >> 4, h = bh & 15;
  const int q0 = qc * 128 + w * 32;
  const int qt = (q0 >> 5);                       // global q-tile = qc*4 + w

  const unsigned short* Qb = Qf + (long)bh * 131072;   // 64 qt * 2048
  const unsigned short* Kb = Kf + (long)bh * 131072;
  const unsigned short* Vb = Vf + (long)bh * 131072;

  // Q fragments (coalesced 16B/lane)
  bf16x8 qf[4];
#pragma unroll
  for (int t = 0; t < 4; ++t)
    qf[t] = *(const bf16x8*)(Qb + ((long)qt * 4 + t) * 512 + l * 8);

  f32x16 o0 = {}, o1 = {};           // O^T frags: rows d in [0,32)/[32,64), col q=l31
  float m = -INFINITY, lsum = 0.f;

  auto stage = [&](int buf, int kt) {
    const unsigned short* gk = Kb + (long)kt * 2048 + tix * 8;
    const unsigned short* gv = Vb + (long)kt * 2048 + tix * 8;
    gl_lds16(gk, (char*)&KLDS[buf][0] + w * 1024);
    gl_lds16(gv, (char*)&VLDS[buf][0] + w * 1024);
  };

  auto process = [&](int buf) {
    bf16x8 kf0 = *(const bf16x8*)&KLDS[buf][0 * 512 + l * 8];
    bf16x8 kf1 = *(const bf16x8*)&KLDS[buf][1 * 512 + l * 8];
    bf16x8 kf2 = *(const bf16x8*)&KLDS[buf][2 * 512 + l * 8];
    bf16x8 kf3 = *(const bf16x8*)&KLDS[buf][3 * 512 + l * 8];

    f32x16 s = {};
    __builtin_amdgcn_s_setprio(1);
    s = mfma32(kf0, qf[0], s);
    s = mfma32(kf1, qf[1], s);
    s = mfma32(kf2, qf[2], s);
    s = mfma32(kf3, qf[3], s);
    __builtin_amdgcn_s_setprio(0);

    bf16x8 vf0 = *(const bf16x8*)&VLDS[buf][0 * 512 + l * 8];
    bf16x8 vf1 = *(const bf16x8*)&VLDS[buf][1 * 512 + l * 8];
    bf16x8 vf2 = *(const bf16x8*)&VLDS[buf][2 * 512 + l * 8];
    bf16x8 vf3 = *(const bf16x8*)&VLDS[buf][3 * 512 + l * 8];

    // tree max over 16 (v_max3), then combine with other half via permlane
    float m0 = fmaxf(fmaxf(s[0], s[1]), s[2]);
    float m1 = fmaxf(fmaxf(s[3], s[4]), s[5]);
    float m2 = fmaxf(fmaxf(s[6], s[7]), s[8]);
    float m3 = fmaxf(fmaxf(s[9], s[10]), s[11]);
    float m4 = fmaxf(fmaxf(s[12], s[13]), s[14]);
    float tm = fmaxf(fmaxf(fmaxf(m0, m1), m2), fmaxf(fmaxf(m3, m4), s[15]));
    tm = fmaxf(tm, xhalf(tm, hi));

    // defer-max (T13): rescale only when running max grows by > 8 (log2 domain)
    if (__any(tm > m + 8.f)) {
      const float mn = fmaxf(m, tm);
      const float al = exp2f(m - mn);
      m = mn;
      lsum *= al;
#pragma unroll
      for (int i = 0; i < 16; ++i) { o0[i] *= al; o1[i] *= al; }
    }

#pragma unroll
    for (int i = 0; i < 16; ++i) s[i] = exp2f(s[i] - m);
    float t0 = (s[0] + s[1]) + (s[2] + s[3]);
    float t1 = (s[4] + s[5]) + (s[6] + s[7]);
    float t2 = (s[8] + s[9]) + (s[10] + s[11]);
    float t3 = (s[12] + s[13]) + (s[14] + s[15]);
    float ts = (t0 + t1) + (t2 + t3);
    lsum += ts + xhalf(ts, hi);

    // P relayout: C-frag -> B-frags via cvt_pk + permlane32_swap
    unsigned W0 = cvtpk_bf16(s[0], s[1]),   W1 = cvtpk_bf16(s[2], s[3]);
    unsigned W2 = cvtpk_bf16(s[4], s[5]),   W3 = cvtpk_bf16(s[6], s[7]);
    unsigned W4 = cvtpk_bf16(s[8], s[9]),   W5 = cvtpk_bf16(s[10], s[11]);
    unsigned W6 = cvtpk_bf16(s[12], s[13]), W7 = cvtpk_bf16(s[14], s[15]);
    const u32x2 r02 = __builtin_amdgcn_permlane32_swap(W0, W2, false, false);
    const u32x2 r13 = __builtin_amdgcn_permlane32_swap(W1, W3, false, false);
    const u32x2 r46 = __builtin_amdgcn_permlane32_swap(W4, W6, false, false);
    const u32x2 r57 = __builtin_amdgcn_permlane32_swap(W5, W7, false, false);
    unsigned af0w[4] = { r02.x, r13.x, r02.y, r13.y };
    unsigned af1w[4] = { r46.x, r57.x, r46.y, r57.y };
    const bf16x8 af0 = *(const bf16x8*)af0w;
    const bf16x8 af1 = *(const bf16x8*)af1w;

    __builtin_amdgcn_s_setprio(1);
    o0 = mfma32(vf0, af0, o0);
    o0 = mfma32(vf1, af1, o0);
    o1 = mfma32(vf2, af0, o1);
    o1 = mfma32(vf3, af1, o1);
    __builtin_amdgcn_s_setprio(0);
  };

  stage(0, 0);
  __syncthreads();
  int buf = 0;
#pragma unroll 1
  for (int kt = 0; kt < 63; ++kt) {
    stage(buf ^ 1, kt + 1);
    process(buf);
    __syncthreads();
    buf ^= 1;
  }
  process(buf);

  const float inv = 1.f / lsum;
  unsigned short* orow = aout + ((b * 2048 + q0 + l31) * 1024 + h * 64);
#pragma unroll
  for (int rg = 0; rg < 4; ++rg) {
    ushort4 v0, v1;
    v0.x = f2bf(o0[rg * 4 + 0] * inv); v0.y = f2bf(o0[rg * 4 + 1] * inv);
    v0.z = f2bf(o0[rg * 4 + 2] * inv); v0.w = f2bf(o0[rg * 4 + 3] * inv);
    v1.x = f2bf(o1[rg * 4 + 0] * inv); v1.y = f2bf(o1[rg * 4 + 1] * inv);
    v1.z = f2bf(o1[rg * 4 + 2] * inv); v1.w = f2bf(o1[rg * 4 + 3] * inv);
    *(ushort4*)(orow + rg * 8 + hi * 4)      = v0;   // d = rg*8 + 4*hi + i
    *(ushort4*)(orow + 32 + rg * 8 + hi * 4) = v1;
  }
}

// ---------------- launch ----------------

extern "C" void kernel_launch(void* const* d_in, const int* in_sizes, int n_in,
                              void* d_out, int out_size, void* d_ws, size_t ws_size,
                              hipStream_t stream) {
  const float* x   = (const float*)d_in[0];
  const float* enc = (const float*)d_in[1];
  const float* nw  = (const float*)d_in[2];
  const float* Wq  = (const float*)d_in[3];
  const float* Wkv = (const float*)d_in[4];
  const float* Wo  = (const float*)d_in[5];
  float* out = (float*)d_out;
  char* ws = (char*)d_ws;
  const long MB = 1024 * 1024;
  unsigned short* xn   = (unsigned short*)(ws);            // 16MB (reused as attn_out)
  unsigned short* encb = (unsigned short*)(ws + 16 * MB);  // 16MB
  unsigned short* wqb  = (unsigned short*)(ws + 32 * MB);  // 2MB
  unsigned short* wkvb = (unsigned short*)(ws + 34 * MB);  // 4MB
  unsigned short* wob  = (unsigned short*)(ws + 38 * MB);  // 2MB
  unsigned short* Qf   = (unsigned short*)(ws + 40 * MB);  // 16MB fragment-order
  unsigned short* Kf   = (unsigned short*)(ws + 56 * MB);  // 16MB fragment-order
  unsigned short* Vf   = (unsigned short*)(ws + 72 * MB);  // 16MB fragment-order
  float* tab           = (float*)(ws + 88 * MB);           // 512KB [j][t] cos/sin
  unsigned short* aout = xn;
  const float* cosT = tab;
  const float* sinT = tab + 65536;

  conv_bf16_k<<<1024, 256, 0, stream>>>(Wq, wqb, 262144);
  conv_bf16_k<<<2048, 256, 0, stream>>>(Wkv, wkvb, 524288);
  conv_bf16_k<<<1024, 256, 0, stream>>>(Wo, wob, 262144);
  conv_bf16_k<<<8192, 256, 0, stream>>>(enc, encb, 2097152);
  rmsnorm_k<<<8192, 256, 0, stream>>>(x, nw, xn);
  rope_tab_k<<<256, 256, 0, stream>>>(tab);
  // Q: RoPE + scale (1/8)*log2(e) fused; fragment layout out
  gemm_bt_k<0><<<dim3(8, 64), 256, 0, stream>>>(xn, wqb, Qf, nullptr, nullptr, nullptr,
                                                cosT, sinT, 0.18033688f, 1024, 1024);
  // K: RoPE (scale 1); V: plain; fragment layouts out
  gemm_bt_k<1><<<dim3(16, 64), 256, 0, stream>>>(encb, wkvb, Kf, Vf, nullptr, nullptr,
                                                 cosT, sinT, 1.0f, 2048, 1024);
  attn_k<<<1024, 256, 0, stream>>>(Qf, Kf, Vf, aout);
  gemm_bt_k<2><<<dim3(8, 64), 256, 0, stream>>>(aout, wob, nullptr, nullptr, out, x,
                                                cosT, sinT, 1.0f, 1024, 1024);
  (void)in_sizes; (void)n_in; (void)out_size; (void)ws_size;
}

// Round 7
// 347.977 us; speedup vs baseline: 1.6835x; 1.0334x over previous
//
#include <hip/hip_runtime.h>
#include <cstdint>

// FlashCrossAttention round 7: barrier-free attention (direct coalesced
// fragment-order loads, reg double-buffer), ones-MFMA row-sum, packed-f32
// softmax math, XCD-swizzled GEMM grids.
// B=4, Td=Te=2048, D=1024, H=16, hd=64.

#define DEVI __device__ __forceinline__

typedef float f32x2 __attribute__((ext_vector_type(2)));
typedef float f32x4 __attribute__((ext_vector_type(4)));
typedef float f32x16 __attribute__((ext_vector_type(16)));
typedef __bf16 bf16x8 __attribute__((ext_vector_type(8)));
typedef unsigned u32x2 __attribute__((ext_vector_type(2)));

DEVI unsigned short f2bf(float f) {
  union { float f; unsigned u; } v; v.f = f;
  unsigned r = v.u + 0x7FFFu + ((v.u >> 16) & 1u);   // RTNE
  return (unsigned short)(r >> 16);
}
DEVI f32x4 mfma16(bf16x8 a, bf16x8 b, f32x4 c) {
  return __builtin_amdgcn_mfma_f32_16x16x32_bf16(a, b, c, 0, 0, 0);
}
DEVI f32x16 mfma32(bf16x8 a, bf16x8 b, f32x16 c) {
  return __builtin_amdgcn_mfma_f32_32x32x16_bf16(a, b, c, 0, 0, 0);
}
DEVI void gl_lds16(const void* g, void* l) {
  __builtin_amdgcn_global_load_lds((const __attribute__((address_space(1))) void*)g,
                                   (__attribute__((address_space(3))) void*)l,
                                   16, 0, 0);
}
DEVI unsigned cvtpk_bf16(float lo, float hi) {
  unsigned r;
  asm("v_cvt_pk_bf16_f32 %0, %1, %2" : "=v"(r) : "v"(lo), "v"(hi));
  return r;
}
DEVI float rexp2(float x) {           // raw v_exp_f32 (exp2)
  float r;
  asm("v_exp_f32 %0, %1" : "=v"(r) : "v"(x));
  return r;
}
DEVI f32x2 max2(f32x2 a, f32x2 b) {
  f32x2 r; r.x = fmaxf(a.x, b.x); r.y = fmaxf(a.y, b.y); return r;
}
// cross-half (lane ^ 32) fetch via permlane32_swap
DEVI float xhalf(float x, int hi) {
  union { float f; unsigned u; } a; a.f = x;
  u32x2 r = __builtin_amdgcn_permlane32_swap(a.u, a.u, false, false);
  union { unsigned u; float f; } o; o.u = hi ? r.x : r.y;
  return o.f;
}

// ---------------- elementwise helpers ----------------

__global__ void conv_bf16_k(const float* __restrict__ in, unsigned short* __restrict__ out, long n4) {
  long i = (long)blockIdx.x * blockDim.x + threadIdx.x;
  if (i >= n4) return;
  const float4 v = ((const float4*)in)[i];
  ushort4 o;
  o.x = f2bf(v.x); o.y = f2bf(v.y); o.z = f2bf(v.z); o.w = f2bf(v.w);
  ((ushort4*)out)[i] = o;
}

__global__ void rmsnorm_k(const float* __restrict__ x, const float* __restrict__ wgt,
                          unsigned short* __restrict__ xn) {
  const int row = blockIdx.x;
  const int t = threadIdx.x;
  const float4 v = ((const float4*)(x + (long)row * 1024))[t];
  float ss = v.x * v.x + v.y * v.y + v.z * v.z + v.w * v.w;
#pragma unroll
  for (int m = 1; m < 64; m <<= 1) ss += __shfl_xor(ss, m, 64);
  __shared__ float red[4];
  if ((t & 63) == 0) red[t >> 6] = ss;
  __syncthreads();
  const float tot = red[0] + red[1] + red[2] + red[3];
  const float rms = rsqrtf(tot * (1.f / 1024.f) + 1e-5f);
  const float4 wv = ((const float4*)wgt)[t];
  ushort4 o;
  o.x = f2bf(v.x * rms * wv.x);
  o.y = f2bf(v.y * rms * wv.y);
  o.z = f2bf(v.z * rms * wv.z);
  o.w = f2bf(v.w * rms * wv.w);
  ((ushort4*)(xn + (long)row * 1024))[t] = o;
}

// cos/sin table layout [j][t]: tab[j*2048 + t] = cos(t*invfreq[j]); +65536 sin
__global__ void rope_tab_k(float* __restrict__ tab) {
  const int i = blockIdx.x * 256 + threadIdx.x;   // 65536 threads
  const int j = i >> 11, t = i & 2047;
  const float inv = powf(10000.f, -(float)j * (1.f / 32.f));
  const float a = (float)t * inv;
  tab[i] = cosf(a);
  tab[65536 + i] = sinf(a);
}

// ---------------- GEMM: C[M,N] = A[M,K] * B^T ----------------
// 1D grid + bijective XCD swizzle (nwg % 8 == 0). nbn = N-tile count.
// EPI 0: RoPE (scale scl) + scatter to Q fragment layout (o_bf0)
// EPI 1: cols<1024: RoPE + K fragment layout; cols>=1024: V fragment layout
// EPI 2: fp32 out = acc + resid
template <int EPI>
__launch_bounds__(256, 2)
__global__ void gemm_bt_k(const unsigned short* __restrict__ A,
                          const unsigned short* __restrict__ Bw,
                          unsigned short* __restrict__ o_bf0,
                          unsigned short* __restrict__ o_bf1,
                          float* __restrict__ o_f32,
                          const float* __restrict__ resid,
                          const float* __restrict__ cosT,
                          const float* __restrict__ sinT,
                          float scl, int nbn, int K) {
  __shared__ unsigned short As[2][128 * 32];
  __shared__ unsigned short Bs[2][128 * 32];
  const int tix = threadIdx.x;
  const int w = tix >> 6, l = tix & 63;
  const int wr = w >> 1, wc = w & 1;
  const int lr = l & 15, lg = l >> 4;
  // XCD-aware bijective swizzle (nwg % 8 == 0)
  const int nwg = gridDim.x;
  const int cpx = nwg >> 3;
  const int swz = ((int)blockIdx.x & 7) * cpx + ((int)blockIdx.x >> 3);
  const long bn = swz % nbn, bm = swz / nbn;
  const long arow0 = bm * 128, brow0 = bn * 128;

  f32x4 acc[4][4] = {};

  const int r2 = tix >> 2, c2 = tix & 3;
  const int sw2 = c2 ^ (r2 & 3);

  auto stage = [&](int buf, int kt) {
    const long k0 = (long)kt * 32;
    const unsigned short* ga  = A  + (arow0 + r2) * K + k0 + sw2 * 8;
    const unsigned short* ga2 = A  + (arow0 + 64 + r2) * K + k0 + sw2 * 8;
    const unsigned short* gb  = Bw + (brow0 + r2) * K + k0 + sw2 * 8;
    const unsigned short* gb2 = Bw + (brow0 + 64 + r2) * K + k0 + sw2 * 8;
    char* la = (char*)&As[buf][0] + w * 1024;
    char* lb = (char*)&Bs[buf][0] + w * 1024;
    gl_lds16(ga,  la);
    gl_lds16(ga2, la + 4096);
    gl_lds16(gb,  lb);
    gl_lds16(gb2, lb + 4096);
  };

  auto lds_off = [&](int row, int chunk) { return row * 32 + ((chunk ^ (row & 3)) << 3); };

  auto compute = [&](int buf) {
    bf16x8 af[4], bv[4];
#pragma unroll
    for (int m = 0; m < 4; ++m)
      af[m] = *(const bf16x8*)&As[buf][lds_off(wr * 64 + m * 16 + lr, lg)];
#pragma unroll
    for (int n = 0; n < 4; ++n)
      bv[n] = *(const bf16x8*)&Bs[buf][lds_off(wc * 64 + n * 16 + lr, lg)];
#pragma unroll
    for (int m = 0; m < 4; ++m)
#pragma unroll
      for (int n = 0; n < 4; ++n)
        acc[m][n] = mfma16(af[m], bv[n], acc[m][n]);
  };

  const int nk = K >> 5;
  stage(0, 0);
  __syncthreads();
  int buf = 0;
#pragma unroll 1
  for (int kt = 0; kt < nk - 1; ++kt) {
    stage(buf ^ 1, kt + 1);
    compute(buf);
    __syncthreads();
    buf ^= 1;
  }
  compute(buf);

  if constexpr (EPI == 2) {
#pragma unroll
    for (int m = 0; m < 4; ++m)
#pragma unroll
      for (int n = 0; n < 4; ++n)
#pragma unroll
        for (int r = 0; r < 4; ++r) {
          const long grow = arow0 + wr * 64 + m * 16 + lg * 4 + r;
          const long gcol = brow0 + wc * 64 + n * 16 + lr;
          const long idx = grow * 1024 + gcol;
          o_f32[idx] = acc[m][n][r] + resid[idx];
        }
    return;
  }

  const long b = arow0 >> 11;                    // batch (tile fits one batch block)
  const bool isV = (EPI == 1) && (brow0 >= 1024);
  const long colbase = isV ? (brow0 - 1024 + wc * 64) : (brow0 + wc * 64);
  const long hh = (colbase >> 6) & 15;
  const long bh = b * 16 + hh;

#pragma unroll
  for (int m = 0; m < 4; ++m) {
    const long tt0 = (arow0 + wr * 64 + m * 16 + lg * 4) & 2047;
    if (!isV) {
      // RoPE path (Q or K): d in {lr, 16+lr, 32+lr, 48+lr}; pairs (lr,32+lr),(16+lr,48+lr)
      const float4 c0 = *(const float4*)(cosT + (long)lr * 2048 + tt0);
      const float4 s0 = *(const float4*)(sinT + (long)lr * 2048 + tt0);
      const float4 c1 = *(const float4*)(cosT + (long)(16 + lr) * 2048 + tt0);
      const float4 s1 = *(const float4*)(sinT + (long)(16 + lr) * 2048 + tt0);
      const int hi_ = (lr >> 3) & 1, j_ = lr & 7;
#pragma unroll
      for (int r = 0; r < 4; ++r) {
        const long tt = tt0 + r;
        const long base = (((bh * 64 + (tt >> 5)) * 4 + 0) * 64 + hi_ * 32 + (tt & 31)) * 8 + j_;
        const float a0 = acc[m][0][r], a1 = acc[m][1][r], a2 = acc[m][2][r], a3 = acc[m][3][r];
        const float cc0 = ((const float*)&c0)[r], ss0 = ((const float*)&s0)[r];
        const float cc1 = ((const float*)&c1)[r], ss1 = ((const float*)&s1)[r];
        o_bf0[base]        = f2bf((a0 * cc0 - a2 * ss0) * scl);
        o_bf0[base + 512]  = f2bf((a1 * cc1 - a3 * ss1) * scl);
        o_bf0[base + 1024] = f2bf((a2 * cc0 + a0 * ss0) * scl);
        o_bf0[base + 1536] = f2bf((a3 * cc1 + a1 * ss1) * scl);
      }
    } else {
      // V path: token tt is the kv position; d in {lr,16+lr,32+lr,48+lr}
#pragma unroll
      for (int r = 0; r < 4; ++r) {
        const long tt = tt0 + r;
        const long kt = tt >> 5, kv5 = tt & 31;
        const long viL = kv5 >> 4, hi_ = (kv5 >> 3) & 1, jj = kv5 & 7;
        const long base = (((bh * 64 + kt) * 4 + viL) * 64 + hi_ * 32 + lr) * 8 + jj;
        o_bf1[base]              = f2bf(acc[m][0][r]);
        o_bf1[base + 128]        = f2bf(acc[m][1][r]);
        o_bf1[base + 1024]       = f2bf(acc[m][2][r]);
        o_bf1[base + 1024 + 128] = f2bf(acc[m][3][r]);
      }
    }
  }
}

// ---------------- flash cross-attention (barrier-free) ----------------
// 1D grid 1024 blocks: bh = blockIdx.x & 63 (XCD locality), qc = blockIdx.x >> 6.
// 4 waves/block, wave owns 32 q rows. Q pre-scaled by log2e/8 (exp2 domain).
// K/V fragment-ordered: tile kt at [bh*131072 + kt*2048 + frag*512 + lane*8].
__launch_bounds__(256, 3)
__global__ void attn_k(const unsigned short* __restrict__ Qf,
                       const unsigned short* __restrict__ Kf,
                       const unsigned short* __restrict__ Vf,
                       unsigned short* __restrict__ aout) {
  const int tix = threadIdx.x;
  const int w = tix >> 6, l = tix & 63;
  const int l31 = l & 31, hi = l >> 5;
  const int bid = blockIdx.x;
  const int bh = bid & 63, qc = bid >> 6;
  const long b = bh >> 4, h = bh & 15;
  const int q0 = qc * 128 + w * 32;
  const int qt = q0 >> 5;

  const unsigned short* Qb = Qf + (long)bh * 131072;
  const unsigned short* Kb = Kf + (long)bh * 131072;
  const unsigned short* Vb = Vf + (long)bh * 131072;

  bf16x8 qf[4];
#pragma unroll
  for (int t = 0; t < 4; ++t)
    qf[t] = *(const bf16x8*)(Qb + ((long)qt * 4 + t) * 512 + l * 8);

  // all-ones bf16 A-frag for the row-sum MFMA
  unsigned onesw[4] = { 0x3F803F80u, 0x3F803F80u, 0x3F803F80u, 0x3F803F80u };
  const bf16x8 ones = *(const bf16x8*)onesw;

  f32x16 o0 = {}, o1 = {}, ex = {};   // O^T frags + row-sum acc
  float m = -INFINITY;

  bf16x8 kA[4], kB[4], vv[4];

  auto loadK = [&](int kt, bf16x8* kf) {
    const unsigned short* p = Kb + (long)kt * 2048 + l * 8;
#pragma unroll
    for (int f = 0; f < 4; ++f) kf[f] = *(const bf16x8*)(p + f * 512);
  };
  auto loadV = [&](int kt, bf16x8* vf) {
    const unsigned short* p = Vb + (long)kt * 2048 + l * 8;
#pragma unroll
    for (int f = 0; f < 4; ++f) vf[f] = *(const bf16x8*)(p + f * 512);
  };

  auto process = [&](const bf16x8* kf, const bf16x8* vf) {
    f32x16 s = {};
    __builtin_amdgcn_s_setprio(1);
    s = mfma32(kf[0], qf[0], s);
    s = mfma32(kf[1], qf[1], s);
    s = mfma32(kf[2], qf[2], s);
    s = mfma32(kf[3], qf[3], s);
    __builtin_amdgcn_s_setprio(0);

    // packed tree max, then cross-half combine
    const f32x2* s2 = (const f32x2*)&s;
    f32x2 a0 = max2(s2[0], s2[1]), a1 = max2(s2[2], s2[3]);
    f32x2 a2 = max2(s2[4], s2[5]), a3 = max2(s2[6], s2[7]);
    a0 = max2(a0, a1); a2 = max2(a2, a3); a0 = max2(a0, a2);
    float tm = fmaxf(a0.x, a0.y);
    tm = fmaxf(tm, xhalf(tm, hi));

    // defer-max (T13): rescale only when running max grows by > 8 (log2 domain)
    if (__any(tm > m + 8.f)) {
      const float mn = fmaxf(m, tm);
      const float al = rexp2(m - mn);
      m = mn;
#pragma unroll
      for (int i = 0; i < 16; ++i) { o0[i] *= al; o1[i] *= al; ex[i] *= al; }
    }

    // p = exp2(s - m) (packed subs + raw v_exp)
    f32x2* sm = (f32x2*)&s;
    const f32x2 mm = { m, m };
#pragma unroll
    for (int i = 0; i < 8; ++i) sm[i] = sm[i] - mm;
#pragma unroll
    for (int i = 0; i < 16; ++i) s[i] = rexp2(s[i]);

    // P relayout: C-frag -> B-frags via cvt_pk + permlane32_swap
    unsigned W0 = cvtpk_bf16(s[0], s[1]),   W1 = cvtpk_bf16(s[2], s[3]);
    unsigned W2 = cvtpk_bf16(s[4], s[5]),   W3 = cvtpk_bf16(s[6], s[7]);
    unsigned W4 = cvtpk_bf16(s[8], s[9]),   W5 = cvtpk_bf16(s[10], s[11]);
    unsigned W6 = cvtpk_bf16(s[12], s[13]), W7 = cvtpk_bf16(s[14], s[15]);
    const u32x2 r02 = __builtin_amdgcn_permlane32_swap(W0, W2, false, false);
    const u32x2 r13 = __builtin_amdgcn_permlane32_swap(W1, W3, false, false);
    const u32x2 r46 = __builtin_amdgcn_permlane32_swap(W4, W6, false, false);
    const u32x2 r57 = __builtin_amdgcn_permlane32_swap(W5, W7, false, false);
    unsigned af0w[4] = { r02.x, r13.x, r02.y, r13.y };
    unsigned af1w[4] = { r46.x, r57.x, r46.y, r57.y };
    const bf16x8 af0 = *(const bf16x8*)af0w;
    const bf16x8 af1 = *(const bf16x8*)af1w;

    __builtin_amdgcn_s_setprio(1);
    o0 = mfma32(vf[0], af0, o0);
    o0 = mfma32(vf[1], af1, o0);
    o1 = mfma32(vf[2], af0, o1);
    o1 = mfma32(vf[3], af1, o1);
    ex = mfma32(ones, af0, ex);       // row-sum: lsum in every elem of ex
    ex = mfma32(ones, af1, ex);
    __builtin_amdgcn_s_setprio(0);
  };

  loadK(0, kA);
#pragma unroll 1
  for (int kt = 0; kt < 62; kt += 2) {
    loadV(kt, vv); loadK(kt + 1, kB);
    process(kA, vv);
    loadV(kt + 1, vv); loadK(kt + 2, kA);
    process(kB, vv);
  }
  loadV(62, vv); loadK(63, kB);
  process(kA, vv);
  loadV(63, vv);
  process(kB, vv);

  const float inv = 1.f / ex[0];
  unsigned short* orow = aout + ((b * 2048 + q0 + l31) * 1024 + h * 64);
#pragma unroll
  for (int rg = 0; rg < 4; ++rg) {
    ushort4 v0, v1;
    v0.x = f2bf(o0[rg * 4 + 0] * inv); v0.y = f2bf(o0[rg * 4 + 1] * inv);
    v0.z = f2bf(o0[rg * 4 + 2] * inv); v0.w = f2bf(o0[rg * 4 + 3] * inv);
    v1.x = f2bf(o1[rg * 4 + 0] * inv); v1.y = f2bf(o1[rg * 4 + 1] * inv);
    v1.z = f2bf(o1[rg * 4 + 2] * inv); v1.w = f2bf(o1[rg * 4 + 3] * inv);
    *(ushort4*)(orow + rg * 8 + hi * 4)      = v0;   // d = rg*8 + 4*hi + i
    *(ushort4*)(orow + 32 + rg * 8 + hi * 4) = v1;
  }
}

// ---------------- launch ----------------

extern "C" void kernel_launch(void* const* d_in, const int* in_sizes, int n_in,
                              void* d_out, int out_size, void* d_ws, size_t ws_size,
                              hipStream_t stream) {
  const float* x   = (const float*)d_in[0];
  const float* enc = (const float*)d_in[1];
  const float* nw  = (const float*)d_in[2];
  const float* Wq  = (const float*)d_in[3];
  const float* Wkv = (const float*)d_in[4];
  const float* Wo  = (const float*)d_in[5];
  float* out = (float*)d_out;
  char* ws = (char*)d_ws;
  const long MB = 1024 * 1024;
  unsigned short* xn   = (unsigned short*)(ws);            // 16MB (reused as attn_out)
  unsigned short* encb = (unsigned short*)(ws + 16 * MB);  // 16MB
  unsigned short* wqb  = (unsigned short*)(ws + 32 * MB);  // 2MB
  unsigned short* wkvb = (unsigned short*)(ws + 34 * MB);  // 4MB
  unsigned short* wob  = (unsigned short*)(ws + 38 * MB);  // 2MB
  unsigned short* Qf   = (unsigned short*)(ws + 40 * MB);  // 16MB fragment-order
  unsigned short* Kf   = (unsigned short*)(ws + 56 * MB);  // 16MB fragment-order
  unsigned short* Vf   = (unsigned short*)(ws + 72 * MB);  // 16MB fragment-order
  float* tab           = (float*)(ws + 88 * MB);           // 512KB [j][t] cos/sin
  unsigned short* aout = xn;
  const float* cosT = tab;
  const float* sinT = tab + 65536;

  conv_bf16_k<<<1024, 256, 0, stream>>>(Wq, wqb, 262144);
  conv_bf16_k<<<2048, 256, 0, stream>>>(Wkv, wkvb, 524288);
  conv_bf16_k<<<1024, 256, 0, stream>>>(Wo, wob, 262144);
  conv_bf16_k<<<8192, 256, 0, stream>>>(enc, encb, 2097152);
  rmsnorm_k<<<8192, 256, 0, stream>>>(x, nw, xn);
  rope_tab_k<<<256, 256, 0, stream>>>(tab);
  // Q: RoPE + scale (1/8)*log2(e) fused; fragment layout out. grid 8x64 -> 512, nbn=8
  gemm_bt_k<0><<<512, 256, 0, stream>>>(xn, wqb, Qf, nullptr, nullptr, nullptr,
                                        cosT, sinT, 0.18033688f, 8, 1024);
  // K: RoPE (scale 1); V: plain. grid 16x64 -> 1024, nbn=16
  gemm_bt_k<1><<<1024, 256, 0, stream>>>(encb, wkvb, Kf, Vf, nullptr, nullptr,
                                         cosT, sinT, 1.0f, 16, 1024);
  attn_k<<<1024, 256, 0, stream>>>(Qf, Kf, Vf, aout);
  gemm_bt_k<2><<<512, 256, 0, stream>>>(aout, wob, nullptr, nullptr, out, x,
                                        cosT, sinT, 1.0f, 8, 1024);
  (void)in_sizes; (void)n_in; (void)out_size; (void)ws_size;
}